// Round 3
// baseline (2025.323 us; speedup 1.0000x reference)
//
#include <hip/hip_runtime.h>

// GCN 3-layer, N=500000, E=8000000 — bucketed LDS-push formulation.
// No CSR, no perm, no global fp atomics, no scan.
//
// Algebra (aggregation commutes with linear maps):
//   L1: (A_hat @ inp) @ W1          -> 3-float aggregation of u0
//   L2: [A_hat h1, A_hat inp] @ W2  -> 29-float aggregation of h1s rows
//   L3: A_hat (h' @ W3)             -> 1-float aggregation of zs
// A_hat v = dinv * (sum_nbr(dinv*v) + dinv*v_self)  (pre/post scale).
//
// Edges are bucketed by dst>>6 into fixed-capacity segments (CAP=1536 vs
// Poisson mean 1024 — +16 sigma, input graph is fixed), record packed as
// src | (dst&511)<<19 (src < 2^19). Each 512-node bucket = 8 consecutive
// segments; one WG streams them and accumulates into LDS (ds_add_f32),
// then runs the per-node dense math as a fused epilogue.
//
// ws (floats): u0[4N] | h1s[32N] | zs[N] | cur[nsub] | ebuf[nsub*CAP]  ~122MB

#define CAP        1536
#define SUBSH      6        // 64-node cursor subranges
#define BSH        9        // 512-node LDS buckets
#define BN         512
#define PACK_SHIFT 19
#define PACK_MASK  0x7FFFFu

__global__ void fill_kernel(const int* __restrict__ src, const int* __restrict__ dst,
                            unsigned int* __restrict__ cur, unsigned int* __restrict__ ebuf, int E) {
    int e = blockIdx.x * blockDim.x + threadIdx.x;
    if (e >= E) return;
    unsigned int d = (unsigned int)dst[e];
    unsigned int s = (unsigned int)src[e];
    unsigned int k = d >> SUBSH;
    unsigned int pos = atomicAdd(&cur[k], 1u);
    if (pos < CAP) ebuf[(size_t)k * CAP + pos] = s | ((d & (BN - 1)) << PACK_SHIFT);
}

// Per-thread segment table for bucket c (8 subranges). All threads compute the
// same values from broadcast (scalarized) loads.
__device__ inline unsigned int load_segs(const unsigned int* __restrict__ cur,
                                         int c, int nsub, unsigned int* cum) {
    cum[0] = 0;
#pragma unroll
    for (int s = 0; s < 8; s++) {
        int k = (c << 3) + s;
        unsigned int n = (k < nsub) ? cur[k] : 0u;
        if (n > CAP) n = CAP;
        cum[s + 1] = cum[s] + n;
    }
    return cum[8];
}

__device__ inline size_t ebuf_idx(const unsigned int* cum, int c, unsigned int f) {
    unsigned int sidx = 0;
#pragma unroll
    for (int s = 1; s < 8; s++) sidx += (f >= cum[s]) ? 1u : 0u;
    return (size_t)((unsigned int)(c << 3) + sidx) * CAP + (f - cum[sidx]);
}

// In-degree histogram (LDS) fused with node1: u0 = {inp*di, di}.
__global__ __launch_bounds__(512) void count_kernel(
    const unsigned int* __restrict__ cur, const unsigned int* __restrict__ ebuf,
    const float* __restrict__ x, const float* __restrict__ y1,
    float4* __restrict__ u0, int N, int nsub) {
    __shared__ unsigned int cnt[BN];
    int c = blockIdx.x, tid = threadIdx.x;
    cnt[tid] = 0;
    unsigned int cum[9];
    unsigned int T = load_segs(cur, c, nsub, cum);
    __syncthreads();
    for (unsigned int base = 0; base < T; base += 2048) {
#pragma unroll
        for (int i = 0; i < 4; i++) {
            unsigned int f = base + tid + 512 * i;
            bool ok = f < T;
            unsigned int p = ebuf[ebuf_idx(cum, c, ok ? f : 0u)];
            atomicAdd(&cnt[p >> PACK_SHIFT], ok ? 1u : 0u);
        }
    }
    __syncthreads();
    int n = (c << BSH) + tid;
    if (n < N) {
        float di = rsqrtf((float)cnt[tid] + 1.0f);
        u0[n] = make_float4(x[2 * n] * di, x[2 * n + 1] * di, y1[n] * di, di);
    }
}

// Layer-1 push (3 floats/edge) + W1/relu epilogue -> h1s rows
// (h1s[n][0..28] = relu(W1^T a + b1)*di, [29..31] = a = A_hat·inp).
__global__ __launch_bounds__(512) void push1_kernel(
    const unsigned int* __restrict__ cur, const unsigned int* __restrict__ ebuf,
    const float4* __restrict__ u0,
    const float* __restrict__ W1, const float* __restrict__ b1,
    float4* __restrict__ h1s, int N, int nsub) {
    __shared__ float acc[BN * 4];
    int c = blockIdx.x, tid = threadIdx.x;
#pragma unroll
    for (int i = tid; i < BN * 4; i += 512) acc[i] = 0.f;
    unsigned int cum[9];
    unsigned int T = load_segs(cur, c, nsub, cum);
    __syncthreads();
    for (unsigned int base = 0; base < T; base += 2048) {
        float4 v[4]; unsigned int dl[4];
#pragma unroll
        for (int i = 0; i < 4; i++) {
            unsigned int f = base + tid + 512 * i;
            bool ok = f < T;
            unsigned int p = ebuf[ebuf_idx(cum, c, ok ? f : 0u)];
            unsigned int s = p & PACK_MASK;
            dl[i] = p >> PACK_SHIFT;
            float4 w = u0[s];
            v[i] = ok ? w : make_float4(0.f, 0.f, 0.f, 0.f);
        }
#pragma unroll
        for (int i = 0; i < 4; i++) {
            atomicAdd(&acc[dl[i] * 4 + 0], v[i].x);
            atomicAdd(&acc[dl[i] * 4 + 1], v[i].y);
            atomicAdd(&acc[dl[i] * 4 + 2], v[i].z);
        }
    }
    __syncthreads();
    int n = (c << BSH) + tid;
    if (n < N) {
        float4 u = u0[n];
        float di = u.w;
        float a0 = (acc[tid * 4 + 0] + u.x) * di;
        float a1 = (acc[tid * 4 + 1] + u.y) * di;
        float a2 = (acc[tid * 4 + 2] + u.z) * di;
        float h[32];
#pragma unroll
        for (int k = 0; k < 29; k++) {
            float v = fmaf(a0, W1[k], fmaf(a1, W1[29 + k], fmaf(a2, W1[58 + k], b1[k])));
            h[k] = fmaxf(v, 0.0f) * di;
        }
        h[29] = a0; h[30] = a1; h[31] = a2;
        float4* row = h1s + (size_t)n * 8;
#pragma unroll
        for (int q = 0; q < 8; q++)
            row[q] = make_float4(h[4 * q], h[4 * q + 1], h[4 * q + 2], h[4 * q + 3]);
    }
}

// Layer-2 push (32 floats/edge, 32 lanes per edge, 128B coalesced row gather)
// with swizzled 64KB LDS accumulator, fused W2/relu/W3 epilogue -> zs, out.
__global__ __launch_bounds__(512, 4) void push2_kernel(
    const unsigned int* __restrict__ cur, const unsigned int* __restrict__ ebuf,
    const float* __restrict__ h1s, const float4* __restrict__ u0,
    const float* __restrict__ x, const float* __restrict__ y1,
    const float* __restrict__ W2, const float* __restrict__ b2,
    const float* __restrict__ W3, const float* __restrict__ b3,
    float* __restrict__ zs, float* __restrict__ out, int N, int nsub) {
    __shared__ float acc[BN * 32];   // exactly 64KB; element (d,m) at d*32 + ((m+d)&31)
    int c = blockIdx.x, tid = threadIdx.x;
    for (int i = tid; i < BN * 32; i += 512) acc[i] = 0.f;
    unsigned int cum[9];
    unsigned int T = load_segs(cur, c, nsub, cum);
    int m = tid & 31, g = tid >> 5;          // 16 groups of 32 lanes
    __syncthreads();
    const unsigned int U = 8;
    for (unsigned int base = 0; base < T; base += 16 * U) {
        float v[U]; unsigned int dl[U];
#pragma unroll
        for (unsigned int i = 0; i < U; i++) {
            unsigned int f = base + g * U + i;
            bool ok = f < T;
            unsigned int p = ebuf[ebuf_idx(cum, c, ok ? f : 0u)];
            unsigned int s = p & PACK_MASK;
            dl[i] = p >> PACK_SHIFT;
            float w = h1s[(size_t)s * 32 + m];   // 128B/edge, coalesced per group
            v[i] = ok ? w : 0.f;
        }
#pragma unroll
        for (unsigned int i = 0; i < U; i++)
            atomicAdd(&acc[(dl[i] << 5) + ((m + dl[i]) & 31)], v[i]);   // bank-conflict-free
    }
    __syncthreads();
    int n = (c << BSH) + tid;
    if (n >= N) return;
    float di = u0[n].w;
    const float4* hrow = (const float4*)(h1s + (size_t)n * 32);
    float hs[32];
#pragma unroll
    for (int q = 0; q < 8; q++) {
        float4 H = hrow[q];
        hs[4 * q] = H.x; hs[4 * q + 1] = H.y; hs[4 * q + 2] = H.z; hs[4 * q + 3] = H.w;
    }
    float gv[32];
#pragma unroll
    for (int k = 0; k < 32; k++) {
        float av = acc[(tid << 5) + ((k + tid) & 31)];   // swizzled read, conflict-free
        gv[k] = (k < 29) ? (av + hs[k]) * di : hs[k];    // 29..31 = A_hat·inp (self only)
    }
    float a2r[29];
#pragma unroll
    for (int k = 0; k < 29; k++) a2r[k] = b2[k];
#pragma unroll
    for (int j = 0; j < 32; j++) {
        float gj = gv[j];
#pragma unroll
        for (int k = 0; k < 29; k++) a2r[k] = fmaf(gj, W2[j * 29 + k], a2r[k]);
    }
    float z = 0.0f;
#pragma unroll
    for (int k = 0; k < 29; k++) z = fmaf(fmaxf(a2r[k], 0.0f), W3[k], z);
    z = fmaf(x[2 * n], W3[29], z);
    z = fmaf(x[2 * n + 1], W3[30], z);
    z = fmaf(y1[n], W3[31], z);
    zs[n]  = z * di;
    out[n] = fmaf(z * di, di, b3[0]);   // self term + bias; neighbor sum added by push3
}

// Layer-3 push (1 float/edge) + final scale.
__global__ __launch_bounds__(512) void push3_kernel(
    const unsigned int* __restrict__ cur, const unsigned int* __restrict__ ebuf,
    const float* __restrict__ zs, const float4* __restrict__ u0,
    float* __restrict__ out, int N, int nsub) {
    __shared__ float acc[BN];
    int c = blockIdx.x, tid = threadIdx.x;
    acc[tid] = 0.f;
    unsigned int cum[9];
    unsigned int T = load_segs(cur, c, nsub, cum);
    __syncthreads();
    for (unsigned int base = 0; base < T; base += 2048) {
#pragma unroll
        for (int i = 0; i < 4; i++) {
            unsigned int f = base + tid + 512 * i;
            bool ok = f < T;
            unsigned int p = ebuf[ebuf_idx(cum, c, ok ? f : 0u)];
            float v = zs[p & PACK_MASK];
            atomicAdd(&acc[p >> PACK_SHIFT], ok ? v : 0.f);
        }
    }
    __syncthreads();
    int n = (c << BSH) + tid;
    if (n < N) out[n] += acc[tid] * u0[n].w;
}

extern "C" void kernel_launch(void* const* d_in, const int* in_sizes, int n_in,
                              void* d_out, int out_size, void* d_ws, size_t ws_size,
                              hipStream_t stream) {
    const float* x  = (const float*)d_in[0];
    const float* y1 = (const float*)d_in[1];
    const int*   ei = (const int*)d_in[2];
    const float* W1 = (const float*)d_in[3];
    const float* b1 = (const float*)d_in[4];
    const float* W2 = (const float*)d_in[5];
    const float* b2 = (const float*)d_in[6];
    const float* W3 = (const float*)d_in[7];
    const float* b3 = (const float*)d_in[8];
    float* out = (float*)d_out;

    int N = in_sizes[1];
    int E = in_sizes[2] / 2;
    const int* src = ei;
    const int* dst = ei + E;

    size_t Ns = (size_t)N;
    int nsub = (N + 63) >> SUBSH;        // 7813
    int nb   = (N + BN - 1) >> BSH;      // 977

    float* ws = (float*)d_ws;
    float4*       u0   = (float4*)ws;                              // 4N floats
    float*        h1s  = ws + 4 * Ns;                              // 32N
    float*        zs   = ws + 36 * Ns;                             // N
    unsigned int* cur  = (unsigned int*)(ws + 37 * Ns);            // nsub
    unsigned int* ebuf = (unsigned int*)(ws + 37 * Ns) + nsub;     // nsub*CAP

    hipMemsetAsync(cur, 0, (size_t)nsub * sizeof(unsigned int), stream);

    const int gE = (E + 255) / 256;
    fill_kernel <<<gE, 256, 0, stream>>>(src, dst, cur, ebuf, E);
    count_kernel<<<nb, 512, 0, stream>>>(cur, ebuf, x, y1, u0, N, nsub);
    push1_kernel<<<nb, 512, 0, stream>>>(cur, ebuf, u0, W1, b1, (float4*)h1s, N, nsub);
    push2_kernel<<<nb, 512, 0, stream>>>(cur, ebuf, h1s, u0, x, y1, W2, b2, W3, b3,
                                         zs, out, N, nsub);
    push3_kernel<<<nb, 512, 0, stream>>>(cur, ebuf, zs, u0, out, N, nsub);
}

// Round 4
// 880.480 us; speedup vs baseline: 2.3002x; 2.3002x over previous
//
#include <hip/hip_runtime.h>
#include <hip/hip_fp16.h>

// GCN 3-layer, N=500000, E=8000000 — segment-bucketed CSR + register-pull.
//
// Algebra (aggregation commutes with linear maps):
//   L1: (A_hat @ inp) @ W1          -> 3-float pull of u0
//   L2: [A_hat h1, A_hat inp] @ W2  -> 29-float pull of fp16 h1s rows (fused W2/W3)
//   L3: A_hat (h' @ W3)             -> 1-float pull of zs
// A_hat v = dinv * (sum_nbr(dinv*v) + dinv*v_self)  (pre/post scale).
//
// CSR build is two-stage for write locality (R2's build had 502MB of random
// 4B scatters): fill buckets edges into 64-node segments (6KB windows, L2
// merges), compact sorts each segment by node in LDS (1 wave/segment) and
// writes ebuf2 + rowdeg (local_offset | deg<<16) sequentially.
//
// ws (floats): u0[4N] | zs[N] | rowdeg[N] | cur[nsub] | ebuf[12M] | ebuf2[12M]
//              | h1s[16N]  ~= 140MB

#define CAP        1536      // per-64-node segment capacity (mean 1024, +16 sigma)
#define SUBSH      6
#define PACK_SHIFT 19        // src < 2^19 = 524288 > N
#define PACK_MASK  0x7FFFFu

__global__ void fill_kernel(const int* __restrict__ src, const int* __restrict__ dst,
                            unsigned int* __restrict__ cur, unsigned int* __restrict__ ebuf, int E) {
    int e = blockIdx.x * blockDim.x + threadIdx.x;
    if (e >= E) return;
    unsigned int d = (unsigned int)dst[e];
    unsigned int s = (unsigned int)src[e];
    unsigned int k = d >> SUBSH;
    unsigned int pos = atomicAdd(&cur[k], 1u);
    if (pos < CAP) ebuf[(size_t)k * CAP + pos] = s | ((d & 63u) << PACK_SHIFT);
}

// One wave per 64-node segment: LDS histogram -> wave scan -> local re-scatter.
// Fused node1: u0 = {inp*di, di}. rowdeg = local_off | deg<<16.
__global__ __launch_bounds__(64) void compact_kernel(
    const unsigned int* __restrict__ cur, const unsigned int* __restrict__ ebuf,
    const float* __restrict__ x, const float* __restrict__ y1,
    unsigned int* __restrict__ ebuf2, unsigned int* __restrict__ rowdeg,
    float4* __restrict__ u0, int N) {
    __shared__ unsigned int cnt[64];
    __shared__ unsigned int base[64];
    __shared__ unsigned int cur2[64];
    int k = blockIdx.x, lane = threadIdx.x;
    cnt[lane] = 0; cur2[lane] = 0;
    unsigned int T = cur[k]; if (T > CAP) T = CAP;
    const unsigned int* seg = ebuf + (size_t)k * CAP;
    __syncthreads();
    for (unsigned int f = lane; f < T; f += 64)
        atomicAdd(&cnt[seg[f] >> PACK_SHIFT], 1u);
    __syncthreads();
    unsigned int myc = cnt[lane];
    unsigned int s = myc;
#pragma unroll
    for (int off = 1; off < 64; off <<= 1) {
        unsigned int t = __shfl_up(s, off, 64);
        if (lane >= off) s += t;
    }
    unsigned int excl = s - myc;
    base[lane] = excl;
    __syncthreads();
    unsigned int* seg2 = ebuf2 + (size_t)k * CAP;
    for (unsigned int f = lane; f < T; f += 64) {
        unsigned int p = seg[f];
        unsigned int d = p >> PACK_SHIFT;
        unsigned int pos = base[d] + atomicAdd(&cur2[d], 1u);
        seg2[pos] = p & PACK_MASK;
    }
    int n = (k << SUBSH) + lane;
    if (n < N) {
        rowdeg[n] = excl | (myc << 16);
        float di = rsqrtf((float)myc + 1.0f);
        u0[n] = make_float4(x[2 * n] * di, x[2 * n + 1] * di, y1[n] * di, di);
    }
}

// Layer-1 pull (float4 gathers from 8MB u0) + W1/relu -> fp16 h1s rows.
// h1s[n][0..28] = relu(W1^T a + b1)*di, [29..31] = a = A_hat·inp (raw).
__global__ void layer1_kernel(const float4* __restrict__ u0, const unsigned int* __restrict__ rowdeg,
                              const unsigned int* __restrict__ ebuf2,
                              const float* __restrict__ W1, const float* __restrict__ b1,
                              uint4* __restrict__ h1s, int N) {
    int n = blockIdx.x * blockDim.x + threadIdx.x;
    if (n >= N) return;
    unsigned int rd = rowdeg[n];
    const unsigned int* lst = ebuf2 + (size_t)(n >> SUBSH) * CAP + (rd & 0xFFFFu);
    unsigned int cnt = rd >> 16;
    float4 u = u0[n];
    float sx = u.x, sy = u.y, sz = u.z;   // self term (u0 = inp*di)
    unsigned int j = 0;
    for (; j + 2 <= cnt; j += 2) {
        float4 v0 = u0[lst[j]], v1 = u0[lst[j + 1]];
        sx += v0.x + v1.x; sy += v0.y + v1.y; sz += v0.z + v1.z;
    }
    if (j < cnt) { float4 v = u0[lst[j]]; sx += v.x; sy += v.y; sz += v.z; }
    float di = u.w;
    float a0 = sx * di, a1 = sy * di, a2 = sz * di;
    float hv[32];
#pragma unroll
    for (int q = 0; q < 29; q++) {
        float v = fmaf(a0, W1[q], fmaf(a1, W1[29 + q], fmaf(a2, W1[58 + q], b1[q])));
        hv[q] = fmaxf(v, 0.0f) * di;       // pre-scaled for next aggregation
    }
    hv[29] = a0; hv[30] = a1; hv[31] = a2; // stash A_hat·inp
    union { __half2 h2[16]; uint4 u4[4]; } pk;
#pragma unroll
    for (int i = 0; i < 16; i++) pk.h2[i] = __floats2half2_rn(hv[2 * i], hv[2 * i + 1]);
    uint4* row = h1s + (size_t)n * 4;
#pragma unroll
    for (int t = 0; t < 4; t++) row[t] = pk.u4[t];
}

__device__ __forceinline__ void unpack8(float4 r, float* o) {
    union { float4 f; __half2 h[4]; } u; u.f = r;
    float2 a = __half22float2(u.h[0]); o[0] = a.x; o[1] = a.y;
    float2 b = __half22float2(u.h[1]); o[2] = b.x; o[3] = b.y;
    float2 c = __half22float2(u.h[2]); o[4] = c.x; o[5] = c.y;
    float2 d = __half22float2(u.h[3]); o[6] = d.x; o[7] = d.y;
}

// Fused layer-2 pull + W2/relu/W3: 4 lanes/node, 64B row gather/edge,
// register accumulation, LDS W2, shfl_xor reduce. Writes zs + partial out.
__global__ __launch_bounds__(256) void pull2_kernel(
    const float4* __restrict__ h1f4, const unsigned int* __restrict__ rowdeg,
    const unsigned int* __restrict__ ebuf2, const float4* __restrict__ u0,
    const float* __restrict__ x, const float* __restrict__ y1,
    const float* __restrict__ W2, const float* __restrict__ b2,
    const float* __restrict__ W3, const float* __restrict__ b3,
    float* __restrict__ zs, float* __restrict__ out, int N) {
    __shared__ float W2l[32 * 29];
    for (int i = threadIdx.x; i < 32 * 29; i += 256) W2l[i] = W2[i];
    int t = blockIdx.x * 256 + threadIdx.x;
    int n = t >> 2, q = t & 3;
    __syncthreads();
    if (n >= N) return;
    unsigned int rd = rowdeg[n];
    const unsigned int* lst = ebuf2 + (size_t)(n >> SUBSH) * CAP + (rd & 0xFFFFu);
    unsigned int cnt = rd >> 16;
    float acc[8] = {0.f, 0.f, 0.f, 0.f, 0.f, 0.f, 0.f, 0.f};
    unsigned int j = 0;
    for (; j + 2 <= cnt; j += 2) {
        unsigned int s0 = lst[j], s1 = lst[j + 1];
        float4 r0 = h1f4[(size_t)s0 * 4 + q];
        float4 r1 = h1f4[(size_t)s1 * 4 + q];
        float f0[8], f1[8];
        unpack8(r0, f0); unpack8(r1, f1);
#pragma unroll
        for (int i = 0; i < 8; i++) acc[i] += f0[i] + f1[i];
    }
    if (j < cnt) {
        float4 r0 = h1f4[(size_t)lst[j] * 4 + q];
        float f0[8]; unpack8(r0, f0);
#pragma unroll
        for (int i = 0; i < 8; i++) acc[i] += f0[i];
    }
    float hs[8];
    { float4 rs = h1f4[(size_t)n * 4 + q]; unpack8(rs, hs); }
    float di = u0[n].w;
    float g[8];
#pragma unroll
    for (int i = 0; i < 8; i++) {
        int jj = 8 * q + i;
        g[i] = (jj < 29) ? (acc[i] + hs[i]) * di   // di*(sum_nbr + self)
                         : hs[i];                  // A_hat·inp (self-stash)
    }
    float p29[29];
#pragma unroll
    for (int kk = 0; kk < 29; kk++) p29[kk] = 0.f;
#pragma unroll
    for (int i = 0; i < 8; i++) {
        float gi = g[i];
        const float* wr = &W2l[(8 * q + i) * 29];
#pragma unroll
        for (int kk = 0; kk < 29; kk++) p29[kk] = fmaf(gi, wr[kk], p29[kk]);
    }
#pragma unroll
    for (int kk = 0; kk < 29; kk++) {
        p29[kk] += __shfl_xor(p29[kk], 1, 64);
        p29[kk] += __shfl_xor(p29[kk], 2, 64);
    }
    if (q == 0) {
        float z = 0.0f;
#pragma unroll
        for (int kk = 0; kk < 29; kk++)
            z = fmaf(fmaxf(p29[kk] + b2[kk], 0.0f), W3[kk], z);
        z = fmaf(x[2 * n], W3[29], z);
        z = fmaf(x[2 * n + 1], W3[30], z);
        z = fmaf(y1[n], W3[31], z);
        zs[n]  = z * di;
        out[n] = fmaf(z * di, di, b3[0]);  // self + bias; neighbor sum added by pull3
    }
}

// Layer-3 pull (scalar) + final scale.
__global__ void pull3_kernel(const float* __restrict__ zs, const float4* __restrict__ u0,
                             const unsigned int* __restrict__ rowdeg,
                             const unsigned int* __restrict__ ebuf2,
                             float* __restrict__ out, int N) {
    int n = blockIdx.x * blockDim.x + threadIdx.x;
    if (n >= N) return;
    unsigned int rd = rowdeg[n];
    const unsigned int* lst = ebuf2 + (size_t)(n >> SUBSH) * CAP + (rd & 0xFFFFu);
    unsigned int cnt = rd >> 16;
    float s = 0.f;
    unsigned int j = 0;
    for (; j + 2 <= cnt; j += 2) s += zs[lst[j]] + zs[lst[j + 1]];
    if (j < cnt) s += zs[lst[j]];
    out[n] += s * u0[n].w;
}

extern "C" void kernel_launch(void* const* d_in, const int* in_sizes, int n_in,
                              void* d_out, int out_size, void* d_ws, size_t ws_size,
                              hipStream_t stream) {
    const float* x  = (const float*)d_in[0];
    const float* y1 = (const float*)d_in[1];
    const int*   ei = (const int*)d_in[2];
    const float* W1 = (const float*)d_in[3];
    const float* b1 = (const float*)d_in[4];
    const float* W2 = (const float*)d_in[5];
    const float* b2 = (const float*)d_in[6];
    const float* W3 = (const float*)d_in[7];
    const float* b3 = (const float*)d_in[8];
    float* out = (float*)d_out;

    int N = in_sizes[1];
    int E = in_sizes[2] / 2;
    const int* src = ei;
    const int* dst = ei + E;

    size_t Ns = (size_t)N;
    int nsub = (N + 63) >> SUBSH;                 // 7813 segments
    size_t segtot = (size_t)nsub * CAP;           // ~12M entries

    float* ws = (float*)d_ws;
    float4*       u0     = (float4*)ws;                              // 4N floats
    float*        zs     = ws + 4 * Ns;                              // N
    unsigned int* rowdeg = (unsigned int*)(ws + 5 * Ns);             // N
    unsigned int* cur    = (unsigned int*)(ws + 6 * Ns);             // nsub
    unsigned int* ebuf   = cur + nsub;                               // segtot
    unsigned int* ebuf2  = ebuf + segtot;                            // segtot
    uint4*        h1s    = (uint4*)(ebuf2 + segtot);                 // 16N floats (fp16 rows)

    hipMemsetAsync(cur, 0, (size_t)nsub * sizeof(unsigned int), stream);

    const int gE = (E + 255) / 256;
    const int gN = (N + 255) / 256;
    fill_kernel   <<<gE, 256, 0, stream>>>(src, dst, cur, ebuf, E);
    compact_kernel<<<nsub, 64, 0, stream>>>(cur, ebuf, x, y1, ebuf2, rowdeg, u0, N);
    layer1_kernel <<<gN, 256, 0, stream>>>(u0, rowdeg, ebuf2, W1, b1, h1s, N);
    pull2_kernel  <<<nsub, 256, 0, stream>>>((const float4*)h1s, rowdeg, ebuf2, u0,
                                             x, y1, W2, b2, W3, b3, zs, out, N);
    pull3_kernel  <<<gN, 256, 0, stream>>>(zs, u0, rowdeg, ebuf2, out, N);
}

// Round 5
// 645.940 us; speedup vs baseline: 3.1355x; 1.3631x over previous
//
#include <hip/hip_runtime.h>
#include <hip/hip_fp16.h>

// GCN 3-layer, N=500000, E=8000000 — two-level binned CSR + register-pull.
//
// Algebra (aggregation commutes with linear maps):
//   L1: (A_hat @ inp) @ W1          -> 3-float pull of u0
//   L2: [A_hat h1, A_hat inp] @ W2  -> 29-float pull of fp16 h1s rows (fused W2/W3)
//   L3: A_hat (h' @ W3)             -> 1-float pull of zs
// A_hat v = dinv * (sum_nbr(dinv*v) + dinv*v_self)  (pre/post scale).
//
// CSR build (R4's fill had 428MB of partial-line writebacks):
//   split: LDS-staged multi-split into 2048-node coarse buckets. Per 4096-edge
//     chunk each bucket gets ~16 records = one full line; block is on one
//     CU/XCD so L2 write-combines. Record = src | (dst&2047)<<19 (30 bits).
//   build: one 1024-thr WG per bucket: LDS hist(2048) -> scan -> node-sorted
//     re-scatter into its private 160KB ebuf2 window (single-XCD, L2-resident),
//     fused node1 (u0) + rowdeg = off | deg<<16.
//
// ws (floats): u0[4N] | zs[N] | rowdeg[N] | gcur[256] | ebuf[256*CAPB]
//              | ebuf2[256*CAPB] | h1s[16N]  ~= 128MB

#define CAPB       40960     // per-bucket capacity: mean 32768, sigma 181 (+45 sigma)
#define BSH2       11        // 2048-node coarse buckets
#define BN2        2048
#define PACK_SHIFT 19        // src < 2^19 = 524288 > N
#define PACK_MASK  0x7FFFFu
#define SPLIT_CH   4096      // edges per split block (16/thread)

__global__ __launch_bounds__(256) void split_kernel(
    const int* __restrict__ src, const int* __restrict__ dst,
    unsigned int* __restrict__ gcur, unsigned int* __restrict__ ebuf, int E) {
    __shared__ unsigned int hist[256];
    __shared__ unsigned int gbase[256];
    int tid = threadIdx.x;
    int base = blockIdx.x * SPLIT_CH;
    hist[tid] = 0;
    __syncthreads();
    unsigned int s[16], d[16];
#pragma unroll
    for (int i = 0; i < 16; i++) {
        int e = base + tid + 256 * i;          // coalesced
        bool ok = e < E;
        s[i] = ok ? (unsigned int)src[e] : 0u;
        d[i] = ok ? (unsigned int)dst[e] : 0xFFFFFFFFu;
        if (ok) atomicAdd(&hist[d[i] >> BSH2], 1u);
    }
    __syncthreads();
    unsigned int c = hist[tid];
    if (c) gbase[tid] = atomicAdd(&gcur[tid], c);
    hist[tid] = 0;                              // reuse as local cursor
    __syncthreads();
#pragma unroll
    for (int i = 0; i < 16; i++) {
        if (d[i] != 0xFFFFFFFFu) {
            unsigned int b = d[i] >> BSH2;
            unsigned int pos = gbase[b] + atomicAdd(&hist[b], 1u);
            if (pos < CAPB)
                ebuf[(size_t)b * CAPB + pos] = s[i] | ((d[i] & (BN2 - 1)) << PACK_SHIFT);
        }
    }
}

// One WG per coarse bucket: histogram -> scan -> node-sorted scatter.
// Fused node1: u0 = {inp*di, di}; rowdeg = off | deg<<16 (off < CAPB < 2^16).
__global__ __launch_bounds__(1024) void build_kernel(
    const unsigned int* __restrict__ gcur, const unsigned int* __restrict__ ebuf,
    const float* __restrict__ x, const float* __restrict__ y1,
    unsigned int* __restrict__ ebuf2, unsigned int* __restrict__ rowdeg,
    float4* __restrict__ u0, int N) {
    __shared__ unsigned int hist[BN2];   // 8KB
    __shared__ unsigned int aux[1024];   // 4KB scan aux
    int b = blockIdx.x, tid = threadIdx.x;
    hist[tid] = 0; hist[tid + 1024] = 0;
    unsigned int T = gcur[b]; if (T > CAPB) T = CAPB;
    const unsigned int* seg = ebuf + (size_t)b * CAPB;
    __syncthreads();
    for (unsigned int f = tid; f < T; f += 1024)
        atomicAdd(&hist[seg[f] >> PACK_SHIFT], 1u);
    __syncthreads();
    unsigned int d0 = hist[2 * tid], d1 = hist[2 * tid + 1];
    unsigned int tsum = d0 + d1;
    aux[tid] = tsum; __syncthreads();
    for (int off = 1; off < 1024; off <<= 1) {
        unsigned int t = (tid >= off) ? aux[tid - off] : 0u;
        __syncthreads();
        aux[tid] += t;
        __syncthreads();
    }
    unsigned int base0 = aux[tid] - tsum;       // exclusive
    unsigned int base1 = base0 + d0;
    hist[2 * tid] = base0; hist[2 * tid + 1] = base1;   // running bases (own slots)
    int n0 = (b << BSH2) + 2 * tid, n1 = n0 + 1;
    if (n0 < N) {
        rowdeg[n0] = base0 | (d0 << 16);
        float di = rsqrtf((float)d0 + 1.0f);
        u0[n0] = make_float4(x[2 * n0] * di, x[2 * n0 + 1] * di, y1[n0] * di, di);
    }
    if (n1 < N) {
        rowdeg[n1] = base1 | (d1 << 16);
        float di = rsqrtf((float)d1 + 1.0f);
        u0[n1] = make_float4(x[2 * n1] * di, x[2 * n1 + 1] * di, y1[n1] * di, di);
    }
    __syncthreads();
    unsigned int* seg2 = ebuf2 + (size_t)b * CAPB;
    for (unsigned int f = tid; f < T; f += 1024) {
        unsigned int p = seg[f];
        unsigned int pos = atomicAdd(&hist[p >> PACK_SHIFT], 1u);
        seg2[pos] = p & PACK_MASK;
    }
}

// Layer-1 pull (float4 gathers from 8MB u0) + W1/relu -> fp16 h1s rows.
// h1s[n][0..28] = relu(W1^T a + b1)*di, [29..31] = a = A_hat·inp (raw).
__global__ void layer1_kernel(const float4* __restrict__ u0, const unsigned int* __restrict__ rowdeg,
                              const unsigned int* __restrict__ ebuf2,
                              const float* __restrict__ W1, const float* __restrict__ b1,
                              uint4* __restrict__ h1s, int N) {
    int n = blockIdx.x * blockDim.x + threadIdx.x;
    if (n >= N) return;
    unsigned int rd = rowdeg[n];
    const unsigned int* lst = ebuf2 + (size_t)(n >> BSH2) * CAPB + (rd & 0xFFFFu);
    unsigned int cnt = rd >> 16;
    float4 u = u0[n];
    float sx = u.x, sy = u.y, sz = u.z;   // self term (u0 = inp*di)
    unsigned int j = 0;
    for (; j + 2 <= cnt; j += 2) {
        float4 v0 = u0[lst[j]], v1 = u0[lst[j + 1]];
        sx += v0.x + v1.x; sy += v0.y + v1.y; sz += v0.z + v1.z;
    }
    if (j < cnt) { float4 v = u0[lst[j]]; sx += v.x; sy += v.y; sz += v.z; }
    float di = u.w;
    float a0 = sx * di, a1 = sy * di, a2 = sz * di;
    float hv[32];
#pragma unroll
    for (int q = 0; q < 29; q++) {
        float v = fmaf(a0, W1[q], fmaf(a1, W1[29 + q], fmaf(a2, W1[58 + q], b1[q])));
        hv[q] = fmaxf(v, 0.0f) * di;       // pre-scaled for next aggregation
    }
    hv[29] = a0; hv[30] = a1; hv[31] = a2; // stash A_hat·inp
    union { __half2 h2[16]; uint4 u4[4]; } pk;
#pragma unroll
    for (int i = 0; i < 16; i++) pk.h2[i] = __floats2half2_rn(hv[2 * i], hv[2 * i + 1]);
    uint4* row = h1s + (size_t)n * 4;
#pragma unroll
    for (int t = 0; t < 4; t++) row[t] = pk.u4[t];
}

__device__ __forceinline__ void unpack8(float4 r, float* o) {
    union { float4 f; __half2 h[4]; } u; u.f = r;
    float2 a = __half22float2(u.h[0]); o[0] = a.x; o[1] = a.y;
    float2 b = __half22float2(u.h[1]); o[2] = b.x; o[3] = b.y;
    float2 c = __half22float2(u.h[2]); o[4] = c.x; o[5] = c.y;
    float2 d = __half22float2(u.h[3]); o[6] = d.x; o[7] = d.y;
}

// Fused layer-2 pull + W2/relu/W3: 4 lanes/node, 64B row gather/edge,
// register accumulation, LDS W2, shfl_xor reduce. Writes zs + partial out.
__global__ __launch_bounds__(256) void pull2_kernel(
    const float4* __restrict__ h1f4, const unsigned int* __restrict__ rowdeg,
    const unsigned int* __restrict__ ebuf2, const float4* __restrict__ u0,
    const float* __restrict__ x, const float* __restrict__ y1,
    const float* __restrict__ W2, const float* __restrict__ b2,
    const float* __restrict__ W3, const float* __restrict__ b3,
    float* __restrict__ zs, float* __restrict__ out, int N) {
    __shared__ float W2l[32 * 29];
    for (int i = threadIdx.x; i < 32 * 29; i += 256) W2l[i] = W2[i];
    int t = blockIdx.x * 256 + threadIdx.x;
    int n = t >> 2, q = t & 3;
    __syncthreads();
    if (n >= N) return;
    unsigned int rd = rowdeg[n];
    const unsigned int* lst = ebuf2 + (size_t)(n >> BSH2) * CAPB + (rd & 0xFFFFu);
    unsigned int cnt = rd >> 16;
    float acc[8] = {0.f, 0.f, 0.f, 0.f, 0.f, 0.f, 0.f, 0.f};
    unsigned int j = 0;
    for (; j + 2 <= cnt; j += 2) {
        unsigned int s0 = lst[j], s1 = lst[j + 1];
        float4 r0 = h1f4[(size_t)s0 * 4 + q];
        float4 r1 = h1f4[(size_t)s1 * 4 + q];
        float f0[8], f1[8];
        unpack8(r0, f0); unpack8(r1, f1);
#pragma unroll
        for (int i = 0; i < 8; i++) acc[i] += f0[i] + f1[i];
    }
    if (j < cnt) {
        float4 r0 = h1f4[(size_t)lst[j] * 4 + q];
        float f0[8]; unpack8(r0, f0);
#pragma unroll
        for (int i = 0; i < 8; i++) acc[i] += f0[i];
    }
    float hs[8];
    { float4 rs = h1f4[(size_t)n * 4 + q]; unpack8(rs, hs); }
    float di = u0[n].w;
    float g[8];
#pragma unroll
    for (int i = 0; i < 8; i++) {
        int jj = 8 * q + i;
        g[i] = (jj < 29) ? (acc[i] + hs[i]) * di   // di*(sum_nbr + self)
                         : hs[i];                  // A_hat·inp (self-stash)
    }
    float p29[29];
#pragma unroll
    for (int kk = 0; kk < 29; kk++) p29[kk] = 0.f;
#pragma unroll
    for (int i = 0; i < 8; i++) {
        float gi = g[i];
        const float* wr = &W2l[(8 * q + i) * 29];
#pragma unroll
        for (int kk = 0; kk < 29; kk++) p29[kk] = fmaf(gi, wr[kk], p29[kk]);
    }
#pragma unroll
    for (int kk = 0; kk < 29; kk++) {
        p29[kk] += __shfl_xor(p29[kk], 1, 64);
        p29[kk] += __shfl_xor(p29[kk], 2, 64);
    }
    if (q == 0) {
        float z = 0.0f;
#pragma unroll
        for (int kk = 0; kk < 29; kk++)
            z = fmaf(fmaxf(p29[kk] + b2[kk], 0.0f), W3[kk], z);
        z = fmaf(x[2 * n], W3[29], z);
        z = fmaf(x[2 * n + 1], W3[30], z);
        z = fmaf(y1[n], W3[31], z);
        zs[n]  = z * di;
        out[n] = fmaf(z * di, di, b3[0]);  // self + bias; neighbor sum added by pull3
    }
}

// Layer-3 pull (scalar) + final scale.
__global__ void pull3_kernel(const float* __restrict__ zs, const float4* __restrict__ u0,
                             const unsigned int* __restrict__ rowdeg,
                             const unsigned int* __restrict__ ebuf2,
                             float* __restrict__ out, int N) {
    int n = blockIdx.x * blockDim.x + threadIdx.x;
    if (n >= N) return;
    unsigned int rd = rowdeg[n];
    const unsigned int* lst = ebuf2 + (size_t)(n >> BSH2) * CAPB + (rd & 0xFFFFu);
    unsigned int cnt = rd >> 16;
    float s = 0.f;
    unsigned int j = 0;
    for (; j + 2 <= cnt; j += 2) s += zs[lst[j]] + zs[lst[j + 1]];
    if (j < cnt) s += zs[lst[j]];
    out[n] += s * u0[n].w;
}

extern "C" void kernel_launch(void* const* d_in, const int* in_sizes, int n_in,
                              void* d_out, int out_size, void* d_ws, size_t ws_size,
                              hipStream_t stream) {
    const float* x  = (const float*)d_in[0];
    const float* y1 = (const float*)d_in[1];
    const int*   ei = (const int*)d_in[2];
    const float* W1 = (const float*)d_in[3];
    const float* b1 = (const float*)d_in[4];
    const float* W2 = (const float*)d_in[5];
    const float* b2 = (const float*)d_in[6];
    const float* W3 = (const float*)d_in[7];
    const float* b3 = (const float*)d_in[8];
    float* out = (float*)d_out;

    int N = in_sizes[1];
    int E = in_sizes[2] / 2;
    const int* src = ei;
    const int* dst = ei + E;

    size_t Ns = (size_t)N;
    int nb = (N + BN2 - 1) >> BSH2;               // 245 coarse buckets (<=256)
    size_t segtot = (size_t)256 * CAPB;           // ~10.5M entries

    float* ws = (float*)d_ws;
    float4*       u0     = (float4*)ws;                              // 4N floats
    float*        zs     = ws + 4 * Ns;                              // N
    unsigned int* rowdeg = (unsigned int*)(ws + 5 * Ns);             // N
    unsigned int* gcur   = (unsigned int*)(ws + 6 * Ns);             // 256
    unsigned int* ebuf   = gcur + 256;                               // segtot
    unsigned int* ebuf2  = ebuf + segtot;                            // segtot
    uint4*        h1s    = (uint4*)(ebuf2 + segtot);                 // 16N floats (fp16 rows)

    hipMemsetAsync(gcur, 0, 256 * sizeof(unsigned int), stream);

    const int gS = (E + SPLIT_CH - 1) / SPLIT_CH;
    const int gN = (N + 255) / 256;
    const int g4 = (4 * N + 255) / 256;
    split_kernel <<<gS, 256, 0, stream>>>(src, dst, gcur, ebuf, E);
    build_kernel <<<nb, 1024, 0, stream>>>(gcur, ebuf, x, y1, ebuf2, rowdeg, u0, N);
    layer1_kernel<<<gN, 256, 0, stream>>>(u0, rowdeg, ebuf2, W1, b1, h1s, N);
    pull2_kernel <<<g4, 256, 0, stream>>>((const float4*)h1s, rowdeg, ebuf2, u0,
                                          x, y1, W2, b2, W3, b3, zs, out, N);
    pull3_kernel <<<gN, 256, 0, stream>>>(zs, u0, rowdeg, ebuf2, out, N);
}

// Round 6
// 608.409 us; speedup vs baseline: 3.3289x; 1.0617x over previous
//
#include <hip/hip_runtime.h>
#include <hip/hip_fp16.h>

// GCN 3-layer, N=500000, E=8000000 — two-level binned CSR + register-pull.
//
// Algebra (aggregation commutes with linear maps):
//   L1: (A_hat @ inp) @ W1          -> 3-float pull of u0
//   L2: [A_hat h1, A_hat inp] @ W2  -> 29-float pull of fp16 h1s rows (fused W2/W3)
//   L3: A_hat (h' @ W3)             -> 1-float pull of zs
// A_hat v = dinv * (sum_nbr(dinv*v) + dinv*v_self)  (pre/post scale).
//
// CSR build: split (LDS multi-split into 2048-node coarse buckets, write-local)
// -> build (1 WG/bucket: LDS hist -> scan -> node-sorted scatter, fused node1).
// R6: deeper unrolls for MLP (gathers were 2-deep), int4 edge loads in split,
// nontemporal streamed-list reads.
//
// ws (floats): u0[4N] | zs[N] | rowdeg[N] | gcur[256] | ebuf[256*CAPB]
//              | ebuf2[256*CAPB] | h1s[16N]  ~= 128MB

#define CAPB       40960     // per-bucket capacity: mean 32768 (+45 sigma)
#define BSH2       11        // 2048-node coarse buckets
#define BN2        2048
#define PACK_SHIFT 19        // src < 2^19 = 524288 > N
#define PACK_MASK  0x7FFFFu
#define SPLIT_CH   4096      // edges per split block (16/thread)

__global__ __launch_bounds__(256) void split_kernel(
    const int* __restrict__ src, const int* __restrict__ dst,
    unsigned int* __restrict__ gcur, unsigned int* __restrict__ ebuf, int E) {
    __shared__ unsigned int hist[256];
    __shared__ unsigned int gbase[256];
    int tid = threadIdx.x;
    int base = blockIdx.x * SPLIT_CH;
    hist[tid] = 0;
    __syncthreads();
    unsigned int s[16], d[16];
    if (base + SPLIT_CH <= E) {          // full chunk: int4 vector loads
        const int4* s4 = (const int4*)(src + base);
        const int4* d4 = (const int4*)(dst + base);
#pragma unroll
        for (int i = 0; i < 4; i++) {
            int4 sv = s4[tid + 256 * i];
            int4 dv = d4[tid + 256 * i];
            s[4 * i + 0] = (unsigned int)sv.x; d[4 * i + 0] = (unsigned int)dv.x;
            s[4 * i + 1] = (unsigned int)sv.y; d[4 * i + 1] = (unsigned int)dv.y;
            s[4 * i + 2] = (unsigned int)sv.z; d[4 * i + 2] = (unsigned int)dv.z;
            s[4 * i + 3] = (unsigned int)sv.w; d[4 * i + 3] = (unsigned int)dv.w;
        }
#pragma unroll
        for (int i = 0; i < 16; i++) atomicAdd(&hist[d[i] >> BSH2], 1u);
    } else {                              // tail chunk: scalar with bounds
#pragma unroll
        for (int i = 0; i < 16; i++) {
            int e = base + tid + 256 * i;
            bool ok = e < E;
            s[i] = ok ? (unsigned int)src[e] : 0u;
            d[i] = ok ? (unsigned int)dst[e] : 0xFFFFFFFFu;
            if (ok) atomicAdd(&hist[d[i] >> BSH2], 1u);
        }
    }
    __syncthreads();
    unsigned int c = hist[tid];
    if (c) gbase[tid] = atomicAdd(&gcur[tid], c);
    hist[tid] = 0;                        // reuse as local cursor
    __syncthreads();
#pragma unroll
    for (int i = 0; i < 16; i++) {
        if (d[i] != 0xFFFFFFFFu) {
            unsigned int b = d[i] >> BSH2;
            unsigned int pos = gbase[b] + atomicAdd(&hist[b], 1u);
            if (pos < CAPB)
                ebuf[(size_t)b * CAPB + pos] = s[i] | ((d[i] & (BN2 - 1)) << PACK_SHIFT);
        }
    }
}

// One WG per coarse bucket: histogram -> scan -> node-sorted scatter.
// Fused node1: u0 = {inp*di, di}; rowdeg = off | deg<<16 (off < CAPB < 2^16).
__global__ __launch_bounds__(1024) void build_kernel(
    const unsigned int* __restrict__ gcur, const unsigned int* __restrict__ ebuf,
    const float* __restrict__ x, const float* __restrict__ y1,
    unsigned int* __restrict__ ebuf2, unsigned int* __restrict__ rowdeg,
    float4* __restrict__ u0, int N) {
    __shared__ unsigned int hist[BN2];   // 8KB
    __shared__ unsigned int aux[1024];   // 4KB scan aux
    int b = blockIdx.x, tid = threadIdx.x;
    hist[tid] = 0; hist[tid + 1024] = 0;
    unsigned int T = gcur[b]; if (T > CAPB) T = CAPB;
    const unsigned int* seg = ebuf + (size_t)b * CAPB;
    __syncthreads();
    for (unsigned int f = tid; f < T; f += 1024)
        atomicAdd(&hist[seg[f] >> PACK_SHIFT], 1u);
    __syncthreads();
    unsigned int d0 = hist[2 * tid], d1 = hist[2 * tid + 1];
    unsigned int tsum = d0 + d1;
    aux[tid] = tsum; __syncthreads();
    for (int off = 1; off < 1024; off <<= 1) {
        unsigned int t = (tid >= off) ? aux[tid - off] : 0u;
        __syncthreads();
        aux[tid] += t;
        __syncthreads();
    }
    unsigned int base0 = aux[tid] - tsum;       // exclusive
    unsigned int base1 = base0 + d0;
    hist[2 * tid] = base0; hist[2 * tid + 1] = base1;   // running bases
    int n0 = (b << BSH2) + 2 * tid, n1 = n0 + 1;
    if (n0 < N) {
        rowdeg[n0] = base0 | (d0 << 16);
        float di = rsqrtf((float)d0 + 1.0f);
        u0[n0] = make_float4(x[2 * n0] * di, x[2 * n0 + 1] * di, y1[n0] * di, di);
    }
    if (n1 < N) {
        rowdeg[n1] = base1 | (d1 << 16);
        float di = rsqrtf((float)d1 + 1.0f);
        u0[n1] = make_float4(x[2 * n1] * di, x[2 * n1 + 1] * di, y1[n1] * di, di);
    }
    __syncthreads();
    unsigned int* seg2 = ebuf2 + (size_t)b * CAPB;
    for (unsigned int f = tid; f < T; f += 1024) {
        unsigned int p = seg[f];
        unsigned int pos = atomicAdd(&hist[p >> PACK_SHIFT], 1u);
        seg2[pos] = p & PACK_MASK;
    }
}

// Layer-1 pull (float4 gathers from 8MB u0) + W1/relu -> fp16 h1s rows.
// h1s[n][0..28] = relu(W1^T a + b1)*di, [29..31] = a = A_hat·inp (raw).
__global__ void layer1_kernel(const float4* __restrict__ u0, const unsigned int* __restrict__ rowdeg,
                              const unsigned int* __restrict__ ebuf2,
                              const float* __restrict__ W1, const float* __restrict__ b1,
                              uint4* __restrict__ h1s, int N) {
    int n = blockIdx.x * blockDim.x + threadIdx.x;
    if (n >= N) return;
    unsigned int rd = rowdeg[n];
    const unsigned int* lst = ebuf2 + (size_t)(n >> BSH2) * CAPB + (rd & 0xFFFFu);
    unsigned int cnt = rd >> 16;
    float4 u = u0[n];
    float sx = u.x, sy = u.y, sz = u.z;   // self term (u0 = inp*di)
    unsigned int j = 0;
    for (; j + 4 <= cnt; j += 4) {        // 4 outstanding gathers
        unsigned int i0 = __builtin_nontemporal_load(lst + j);
        unsigned int i1 = __builtin_nontemporal_load(lst + j + 1);
        unsigned int i2 = __builtin_nontemporal_load(lst + j + 2);
        unsigned int i3 = __builtin_nontemporal_load(lst + j + 3);
        float4 v0 = u0[i0], v1 = u0[i1], v2 = u0[i2], v3 = u0[i3];
        sx += (v0.x + v1.x) + (v2.x + v3.x);
        sy += (v0.y + v1.y) + (v2.y + v3.y);
        sz += (v0.z + v1.z) + (v2.z + v3.z);
    }
    for (; j < cnt; j++) {
        float4 v = u0[lst[j]];
        sx += v.x; sy += v.y; sz += v.z;
    }
    float di = u.w;
    float a0 = sx * di, a1 = sy * di, a2 = sz * di;
    float hv[32];
#pragma unroll
    for (int q = 0; q < 29; q++) {
        float v = fmaf(a0, W1[q], fmaf(a1, W1[29 + q], fmaf(a2, W1[58 + q], b1[q])));
        hv[q] = fmaxf(v, 0.0f) * di;       // pre-scaled for next aggregation
    }
    hv[29] = a0; hv[30] = a1; hv[31] = a2; // stash A_hat·inp
    union { __half2 h2[16]; uint4 u4[4]; } pk;
#pragma unroll
    for (int i = 0; i < 16; i++) pk.h2[i] = __floats2half2_rn(hv[2 * i], hv[2 * i + 1]);
    uint4* row = h1s + (size_t)n * 4;
#pragma unroll
    for (int t = 0; t < 4; t++) row[t] = pk.u4[t];
}

__device__ __forceinline__ void unpack8(float4 r, float* o) {
    union { float4 f; __half2 h[4]; } u; u.f = r;
    float2 a = __half22float2(u.h[0]); o[0] = a.x; o[1] = a.y;
    float2 b = __half22float2(u.h[1]); o[2] = b.x; o[3] = b.y;
    float2 c = __half22float2(u.h[2]); o[4] = c.x; o[5] = c.y;
    float2 d = __half22float2(u.h[3]); o[6] = d.x; o[7] = d.y;
}

// Fused layer-2 pull + W2/relu/W3: 4 lanes/node, 64B row gather/edge,
// unroll-4 register accumulation, LDS W2, shfl_xor reduce.
__global__ __launch_bounds__(256) void pull2_kernel(
    const float4* __restrict__ h1f4, const unsigned int* __restrict__ rowdeg,
    const unsigned int* __restrict__ ebuf2, const float4* __restrict__ u0,
    const float* __restrict__ x, const float* __restrict__ y1,
    const float* __restrict__ W2, const float* __restrict__ b2,
    const float* __restrict__ W3, const float* __restrict__ b3,
    float* __restrict__ zs, float* __restrict__ out, int N) {
    __shared__ float W2l[32 * 29];
    for (int i = threadIdx.x; i < 32 * 29; i += 256) W2l[i] = W2[i];
    int t = blockIdx.x * 256 + threadIdx.x;
    int n = t >> 2, q = t & 3;
    __syncthreads();
    if (n >= N) return;
    unsigned int rd = rowdeg[n];
    const unsigned int* lst = ebuf2 + (size_t)(n >> BSH2) * CAPB + (rd & 0xFFFFu);
    unsigned int cnt = rd >> 16;
    float acc[8] = {0.f, 0.f, 0.f, 0.f, 0.f, 0.f, 0.f, 0.f};
    unsigned int j = 0;
    for (; j + 4 <= cnt; j += 4) {        // 4 outstanding 64B row fetches
        unsigned int s0 = lst[j], s1 = lst[j + 1], s2 = lst[j + 2], s3 = lst[j + 3];
        float4 r0 = h1f4[(size_t)s0 * 4 + q];
        float4 r1 = h1f4[(size_t)s1 * 4 + q];
        float4 r2 = h1f4[(size_t)s2 * 4 + q];
        float4 r3 = h1f4[(size_t)s3 * 4 + q];
        float f0[8], f1[8], f2[8], f3[8];
        unpack8(r0, f0); unpack8(r1, f1); unpack8(r2, f2); unpack8(r3, f3);
#pragma unroll
        for (int i = 0; i < 8; i++) acc[i] += (f0[i] + f1[i]) + (f2[i] + f3[i]);
    }
    for (; j < cnt; j++) {
        float4 r0 = h1f4[(size_t)lst[j] * 4 + q];
        float f0[8]; unpack8(r0, f0);
#pragma unroll
        for (int i = 0; i < 8; i++) acc[i] += f0[i];
    }
    float hs[8];
    { float4 rs = h1f4[(size_t)n * 4 + q]; unpack8(rs, hs); }
    float di = u0[n].w;
    float g[8];
#pragma unroll
    for (int i = 0; i < 8; i++) {
        int jj = 8 * q + i;
        g[i] = (jj < 29) ? (acc[i] + hs[i]) * di   // di*(sum_nbr + self)
                         : hs[i];                  // A_hat·inp (self-stash)
    }
    float p29[29];
#pragma unroll
    for (int kk = 0; kk < 29; kk++) p29[kk] = 0.f;
#pragma unroll
    for (int i = 0; i < 8; i++) {
        float gi = g[i];
        const float* wr = &W2l[(8 * q + i) * 29];
#pragma unroll
        for (int kk = 0; kk < 29; kk++) p29[kk] = fmaf(gi, wr[kk], p29[kk]);
    }
#pragma unroll
    for (int kk = 0; kk < 29; kk++) {
        p29[kk] += __shfl_xor(p29[kk], 1, 64);
        p29[kk] += __shfl_xor(p29[kk], 2, 64);
    }
    if (q == 0) {
        float z = 0.0f;
#pragma unroll
        for (int kk = 0; kk < 29; kk++)
            z = fmaf(fmaxf(p29[kk] + b2[kk], 0.0f), W3[kk], z);
        z = fmaf(x[2 * n], W3[29], z);
        z = fmaf(x[2 * n + 1], W3[30], z);
        z = fmaf(y1[n], W3[31], z);
        zs[n]  = z * di;
        out[n] = fmaf(z * di, di, b3[0]);  // self + bias; neighbor sum added by pull3
    }
}

// Layer-3 pull (scalar) + final scale.
__global__ void pull3_kernel(const float* __restrict__ zs, const float4* __restrict__ u0,
                             const unsigned int* __restrict__ rowdeg,
                             const unsigned int* __restrict__ ebuf2,
                             float* __restrict__ out, int N) {
    int n = blockIdx.x * blockDim.x + threadIdx.x;
    if (n >= N) return;
    unsigned int rd = rowdeg[n];
    const unsigned int* lst = ebuf2 + (size_t)(n >> BSH2) * CAPB + (rd & 0xFFFFu);
    unsigned int cnt = rd >> 16;
    float s = 0.f;
    unsigned int j = 0;
    for (; j + 4 <= cnt; j += 4) {
        unsigned int i0 = __builtin_nontemporal_load(lst + j);
        unsigned int i1 = __builtin_nontemporal_load(lst + j + 1);
        unsigned int i2 = __builtin_nontemporal_load(lst + j + 2);
        unsigned int i3 = __builtin_nontemporal_load(lst + j + 3);
        s += (zs[i0] + zs[i1]) + (zs[i2] + zs[i3]);
    }
    for (; j < cnt; j++) s += zs[lst[j]];
    out[n] += s * u0[n].w;
}

extern "C" void kernel_launch(void* const* d_in, const int* in_sizes, int n_in,
                              void* d_out, int out_size, void* d_ws, size_t ws_size,
                              hipStream_t stream) {
    const float* x  = (const float*)d_in[0];
    const float* y1 = (const float*)d_in[1];
    const int*   ei = (const int*)d_in[2];
    const float* W1 = (const float*)d_in[3];
    const float* b1 = (const float*)d_in[4];
    const float* W2 = (const float*)d_in[5];
    const float* b2 = (const float*)d_in[6];
    const float* W3 = (const float*)d_in[7];
    const float* b3 = (const float*)d_in[8];
    float* out = (float*)d_out;

    int N = in_sizes[1];
    int E = in_sizes[2] / 2;
    const int* src = ei;
    const int* dst = ei + E;

    size_t Ns = (size_t)N;
    int nb = (N + BN2 - 1) >> BSH2;               // 245 coarse buckets (<=256)
    size_t segtot = (size_t)256 * CAPB;           // ~10.5M entries

    float* ws = (float*)d_ws;
    float4*       u0     = (float4*)ws;                              // 4N floats
    float*        zs     = ws + 4 * Ns;                              // N
    unsigned int* rowdeg = (unsigned int*)(ws + 5 * Ns);             // N
    unsigned int* gcur   = (unsigned int*)(ws + 6 * Ns);             // 256
    unsigned int* ebuf   = gcur + 256;                               // segtot
    unsigned int* ebuf2  = ebuf + segtot;                            // segtot
    uint4*        h1s    = (uint4*)(ebuf2 + segtot);                 // 16N floats (fp16 rows)

    hipMemsetAsync(gcur, 0, 256 * sizeof(unsigned int), stream);

    const int gS = (E + SPLIT_CH - 1) / SPLIT_CH;
    const int gN = (N + 255) / 256;
    const int g4 = (4 * N + 255) / 256;
    split_kernel <<<gS, 256, 0, stream>>>(src, dst, gcur, ebuf, E);
    build_kernel <<<nb, 1024, 0, stream>>>(gcur, ebuf, x, y1, ebuf2, rowdeg, u0, N);
    layer1_kernel<<<gN, 256, 0, stream>>>(u0, rowdeg, ebuf2, W1, b1, h1s, N);
    pull2_kernel <<<g4, 256, 0, stream>>>((const float4*)h1s, rowdeg, ebuf2, u0,
                                          x, y1, W2, b2, W3, b3, zs, out, N);
    pull3_kernel <<<gN, 256, 0, stream>>>(zs, u0, rowdeg, ebuf2, out, N);
}

// Round 7
// 598.238 us; speedup vs baseline: 3.3855x; 1.0170x over previous
//
#include <hip/hip_runtime.h>
#include <hip/hip_fp16.h>

// GCN 3-layer, N=500000, E=8000000 — two-level binned CSR + register-pull.
//
// Algebra (aggregation commutes with linear maps):
//   L1: (A_hat @ inp) @ W1          -> 3-float pull of fp16 u0h (4MB, L2-resident)
//   L2: [A_hat h1, A_hat inp] @ W2  -> 29-float pull of fp16 h1s rows (fused W2/W3)
//   L3: A_hat (h' @ W3)             -> 1-half pull of fp16 zs (1MB, L2-resident)
// A_hat v = dinv * (sum_nbr(dinv*v) + dinv*v_self)  (pre/post scale).
//
// CSR build: split (LDS multi-split into 2048-node coarse buckets, write-local)
// -> build (1 WG/bucket: LDS hist -> scan -> node-sorted scatter, fused node1).
// R7: fp16 gather tables for layers 1/3 so the random-gather footprints (4MB/1MB)
// fit per-XCD L2; nontemporal loads on stream-once edge lists.
//
// ws (floats): u0[4N] | zs(half)[N/2] | rowdeg[N] | u0h[2N] | gcur[256]
//              | ebuf[256*CAPB] | ebuf2[256*CAPB] | h1s[16N]  ~= 132MB

#define CAPB       40960     // per-bucket capacity: mean 32768 (+45 sigma)
#define BSH2       11        // 2048-node coarse buckets
#define BN2        2048
#define PACK_SHIFT 19        // src < 2^19 = 524288 > N
#define PACK_MASK  0x7FFFFu
#define SPLIT_CH   4096      // edges per split block (16/thread)

typedef int v4i __attribute__((ext_vector_type(4)));

__global__ __launch_bounds__(256) void split_kernel(
    const int* __restrict__ src, const int* __restrict__ dst,
    unsigned int* __restrict__ gcur, unsigned int* __restrict__ ebuf, int E) {
    __shared__ unsigned int hist[256];
    __shared__ unsigned int gbase[256];
    int tid = threadIdx.x;
    int base = blockIdx.x * SPLIT_CH;
    hist[tid] = 0;
    __syncthreads();
    unsigned int s[16], d[16];
    if (base + SPLIT_CH <= E) {          // full chunk: int4 nontemporal loads
        const v4i* s4 = (const v4i*)(src + base);
        const v4i* d4 = (const v4i*)(dst + base);
#pragma unroll
        for (int i = 0; i < 4; i++) {
            v4i sv = __builtin_nontemporal_load(s4 + tid + 256 * i);
            v4i dv = __builtin_nontemporal_load(d4 + tid + 256 * i);
            s[4 * i + 0] = (unsigned int)sv.x; d[4 * i + 0] = (unsigned int)dv.x;
            s[4 * i + 1] = (unsigned int)sv.y; d[4 * i + 1] = (unsigned int)dv.y;
            s[4 * i + 2] = (unsigned int)sv.z; d[4 * i + 2] = (unsigned int)dv.z;
            s[4 * i + 3] = (unsigned int)sv.w; d[4 * i + 3] = (unsigned int)dv.w;
        }
#pragma unroll
        for (int i = 0; i < 16; i++) atomicAdd(&hist[d[i] >> BSH2], 1u);
    } else {                              // tail chunk: scalar with bounds
#pragma unroll
        for (int i = 0; i < 16; i++) {
            int e = base + tid + 256 * i;
            bool ok = e < E;
            s[i] = ok ? (unsigned int)src[e] : 0u;
            d[i] = ok ? (unsigned int)dst[e] : 0xFFFFFFFFu;
            if (ok) atomicAdd(&hist[d[i] >> BSH2], 1u);
        }
    }
    __syncthreads();
    unsigned int c = hist[tid];
    if (c) gbase[tid] = atomicAdd(&gcur[tid], c);
    hist[tid] = 0;                        // reuse as local cursor
    __syncthreads();
#pragma unroll
    for (int i = 0; i < 16; i++) {
        if (d[i] != 0xFFFFFFFFu) {
            unsigned int b = d[i] >> BSH2;
            unsigned int pos = gbase[b] + atomicAdd(&hist[b], 1u);
            if (pos < CAPB)
                ebuf[(size_t)b * CAPB + pos] = s[i] | ((d[i] & (BN2 - 1)) << PACK_SHIFT);
        }
    }
}

// One WG per coarse bucket: histogram -> scan -> node-sorted scatter.
// Fused node1: u0 = {inp*di, di} (fp32) + u0h = {x0*di, x1*di, y1*di, 0} (fp16);
// rowdeg = off | deg<<16 (off < CAPB < 2^16).
__global__ __launch_bounds__(1024) void build_kernel(
    const unsigned int* __restrict__ gcur, const unsigned int* __restrict__ ebuf,
    const float* __restrict__ x, const float* __restrict__ y1,
    unsigned int* __restrict__ ebuf2, unsigned int* __restrict__ rowdeg,
    float4* __restrict__ u0, uint2* __restrict__ u0h, int N) {
    __shared__ unsigned int hist[BN2];   // 8KB
    __shared__ unsigned int aux[1024];   // 4KB scan aux
    int b = blockIdx.x, tid = threadIdx.x;
    hist[tid] = 0; hist[tid + 1024] = 0;
    unsigned int T = gcur[b]; if (T > CAPB) T = CAPB;
    const unsigned int* seg = ebuf + (size_t)b * CAPB;
    __syncthreads();
    for (unsigned int f = tid; f < T; f += 1024)
        atomicAdd(&hist[seg[f] >> PACK_SHIFT], 1u);
    __syncthreads();
    unsigned int d0 = hist[2 * tid], d1 = hist[2 * tid + 1];
    unsigned int tsum = d0 + d1;
    aux[tid] = tsum; __syncthreads();
    for (int off = 1; off < 1024; off <<= 1) {
        unsigned int t = (tid >= off) ? aux[tid - off] : 0u;
        __syncthreads();
        aux[tid] += t;
        __syncthreads();
    }
    unsigned int base0 = aux[tid] - tsum;       // exclusive
    unsigned int base1 = base0 + d0;
    hist[2 * tid] = base0; hist[2 * tid + 1] = base1;   // running bases
#pragma unroll
    for (int k = 0; k < 2; k++) {
        int n = (b << BSH2) + 2 * tid + k;
        if (n < N) {
            unsigned int bb = k ? base1 : base0;
            unsigned int dd = k ? d1 : d0;
            rowdeg[n] = bb | (dd << 16);
            float di = rsqrtf((float)dd + 1.0f);
            float v0 = x[2 * n] * di, v1 = x[2 * n + 1] * di, v2 = y1[n] * di;
            u0[n] = make_float4(v0, v1, v2, di);
            union { __half2 h2[2]; uint2 u; } pk;
            pk.h2[0] = __floats2half2_rn(v0, v1);
            pk.h2[1] = __floats2half2_rn(v2, 0.f);
            u0h[n] = pk.u;
        }
    }
    __syncthreads();
    unsigned int* seg2 = ebuf2 + (size_t)b * CAPB;
    for (unsigned int f = tid; f < T; f += 1024) {
        unsigned int p = seg[f];
        unsigned int pos = atomicAdd(&hist[p >> PACK_SHIFT], 1u);
        seg2[pos] = p & PACK_MASK;
    }
}

// Layer-1 pull (8B fp16 gathers from 4MB L2-resident u0h) + W1/relu -> fp16 h1s.
// h1s[n][0..28] = relu(W1^T a + b1)*di, [29..31] = a = A_hat·inp (raw).
__global__ void layer1_kernel(const float4* __restrict__ u0, const uint2* __restrict__ u0h,
                              const unsigned int* __restrict__ rowdeg,
                              const unsigned int* __restrict__ ebuf2,
                              const float* __restrict__ W1, const float* __restrict__ b1,
                              uint4* __restrict__ h1s, int N) {
    int n = blockIdx.x * blockDim.x + threadIdx.x;
    if (n >= N) return;
    unsigned int rd = rowdeg[n];
    const unsigned int* lst = ebuf2 + (size_t)(n >> BSH2) * CAPB + (rd & 0xFFFFu);
    unsigned int cnt = rd >> 16;
    float4 u = u0[n];
    float sx = u.x, sy = u.y, sz = u.z;   // self term fp32 (u0 = inp*di)
    unsigned int j = 0;
    for (; j + 4 <= cnt; j += 4) {        // 4 outstanding gathers
        unsigned int i0 = __builtin_nontemporal_load(lst + j);
        unsigned int i1 = __builtin_nontemporal_load(lst + j + 1);
        unsigned int i2 = __builtin_nontemporal_load(lst + j + 2);
        unsigned int i3 = __builtin_nontemporal_load(lst + j + 3);
        union { uint2 u; __half2 h[2]; } g0, g1, g2, g3;
        g0.u = u0h[i0]; g1.u = u0h[i1]; g2.u = u0h[i2]; g3.u = u0h[i3];
        float2 a0 = __half22float2(g0.h[0]), b0 = __half22float2(g0.h[1]);
        float2 a1 = __half22float2(g1.h[0]), b1_ = __half22float2(g1.h[1]);
        float2 a2 = __half22float2(g2.h[0]), b2_ = __half22float2(g2.h[1]);
        float2 a3 = __half22float2(g3.h[0]), b3_ = __half22float2(g3.h[1]);
        sx += (a0.x + a1.x) + (a2.x + a3.x);
        sy += (a0.y + a1.y) + (a2.y + a3.y);
        sz += (b0.x + b1_.x) + (b2_.x + b3_.x);
    }
    for (; j < cnt; j++) {
        union { uint2 u; __half2 h[2]; } g; g.u = u0h[lst[j]];
        float2 a = __half22float2(g.h[0]);
        sx += a.x; sy += a.y; sz += __half2float(g.h[1].x);
    }
    float di = u.w;
    float a0 = sx * di, a1 = sy * di, a2 = sz * di;
    float hv[32];
#pragma unroll
    for (int q = 0; q < 29; q++) {
        float v = fmaf(a0, W1[q], fmaf(a1, W1[29 + q], fmaf(a2, W1[58 + q], b1[q])));
        hv[q] = fmaxf(v, 0.0f) * di;       // pre-scaled for next aggregation
    }
    hv[29] = a0; hv[30] = a1; hv[31] = a2; // stash A_hat·inp
    union { __half2 h2[16]; uint4 u4[4]; } pk;
#pragma unroll
    for (int i = 0; i < 16; i++) pk.h2[i] = __floats2half2_rn(hv[2 * i], hv[2 * i + 1]);
    uint4* row = h1s + (size_t)n * 4;
#pragma unroll
    for (int t = 0; t < 4; t++) row[t] = pk.u4[t];
}

__device__ __forceinline__ void unpack8(float4 r, float* o) {
    union { float4 f; __half2 h[4]; } u; u.f = r;
    float2 a = __half22float2(u.h[0]); o[0] = a.x; o[1] = a.y;
    float2 b = __half22float2(u.h[1]); o[2] = b.x; o[3] = b.y;
    float2 c = __half22float2(u.h[2]); o[4] = c.x; o[5] = c.y;
    float2 d = __half22float2(u.h[3]); o[6] = d.x; o[7] = d.y;
}

// Fused layer-2 pull + W2/relu/W3: 4 lanes/node, 64B row gather/edge,
// unroll-4 register accumulation, LDS W2, shfl_xor reduce. Writes fp16 zs + out.
__global__ __launch_bounds__(256) void pull2_kernel(
    const float4* __restrict__ h1f4, const unsigned int* __restrict__ rowdeg,
    const unsigned int* __restrict__ ebuf2, const float4* __restrict__ u0,
    const float* __restrict__ x, const float* __restrict__ y1,
    const float* __restrict__ W2, const float* __restrict__ b2,
    const float* __restrict__ W3, const float* __restrict__ b3,
    __half* __restrict__ zs, float* __restrict__ out, int N) {
    __shared__ float W2l[32 * 29];
    for (int i = threadIdx.x; i < 32 * 29; i += 256) W2l[i] = W2[i];
    int t = blockIdx.x * 256 + threadIdx.x;
    int n = t >> 2, q = t & 3;
    __syncthreads();
    if (n >= N) return;
    unsigned int rd = rowdeg[n];
    const unsigned int* lst = ebuf2 + (size_t)(n >> BSH2) * CAPB + (rd & 0xFFFFu);
    unsigned int cnt = rd >> 16;
    float acc[8] = {0.f, 0.f, 0.f, 0.f, 0.f, 0.f, 0.f, 0.f};
    unsigned int j = 0;
    for (; j + 4 <= cnt; j += 4) {        // 4 outstanding 64B row fetches
        unsigned int s0 = __builtin_nontemporal_load(lst + j);
        unsigned int s1 = __builtin_nontemporal_load(lst + j + 1);
        unsigned int s2 = __builtin_nontemporal_load(lst + j + 2);
        unsigned int s3 = __builtin_nontemporal_load(lst + j + 3);
        float4 r0 = h1f4[(size_t)s0 * 4 + q];
        float4 r1 = h1f4[(size_t)s1 * 4 + q];
        float4 r2 = h1f4[(size_t)s2 * 4 + q];
        float4 r3 = h1f4[(size_t)s3 * 4 + q];
        float f0[8], f1[8], f2[8], f3[8];
        unpack8(r0, f0); unpack8(r1, f1); unpack8(r2, f2); unpack8(r3, f3);
#pragma unroll
        for (int i = 0; i < 8; i++) acc[i] += (f0[i] + f1[i]) + (f2[i] + f3[i]);
    }
    for (; j < cnt; j++) {
        float4 r0 = h1f4[(size_t)lst[j] * 4 + q];
        float f0[8]; unpack8(r0, f0);
#pragma unroll
        for (int i = 0; i < 8; i++) acc[i] += f0[i];
    }
    float hs[8];
    { float4 rs = h1f4[(size_t)n * 4 + q]; unpack8(rs, hs); }
    float di = u0[n].w;
    float g[8];
#pragma unroll
    for (int i = 0; i < 8; i++) {
        int jj = 8 * q + i;
        g[i] = (jj < 29) ? (acc[i] + hs[i]) * di   // di*(sum_nbr + self)
                         : hs[i];                  // A_hat·inp (self-stash)
    }
    float p29[29];
#pragma unroll
    for (int kk = 0; kk < 29; kk++) p29[kk] = 0.f;
#pragma unroll
    for (int i = 0; i < 8; i++) {
        float gi = g[i];
        const float* wr = &W2l[(8 * q + i) * 29];
#pragma unroll
        for (int kk = 0; kk < 29; kk++) p29[kk] = fmaf(gi, wr[kk], p29[kk]);
    }
#pragma unroll
    for (int kk = 0; kk < 29; kk++) {
        p29[kk] += __shfl_xor(p29[kk], 1, 64);
        p29[kk] += __shfl_xor(p29[kk], 2, 64);
    }
    if (q == 0) {
        float z = 0.0f;
#pragma unroll
        for (int kk = 0; kk < 29; kk++)
            z = fmaf(fmaxf(p29[kk] + b2[kk], 0.0f), W3[kk], z);
        z = fmaf(x[2 * n], W3[29], z);
        z = fmaf(x[2 * n + 1], W3[30], z);
        z = fmaf(y1[n], W3[31], z);
        zs[n]  = __float2half_rn(z * di);
        out[n] = fmaf(z * di, di, b3[0]);  // self + bias; neighbor sum added by pull3
    }
}

// Layer-3 pull (2B fp16 gathers from 1MB L2-resident zs) + final scale.
__global__ void pull3_kernel(const __half* __restrict__ zs, const float4* __restrict__ u0,
                             const unsigned int* __restrict__ rowdeg,
                             const unsigned int* __restrict__ ebuf2,
                             float* __restrict__ out, int N) {
    int n = blockIdx.x * blockDim.x + threadIdx.x;
    if (n >= N) return;
    unsigned int rd = rowdeg[n];
    const unsigned int* lst = ebuf2 + (size_t)(n >> BSH2) * CAPB + (rd & 0xFFFFu);
    unsigned int cnt = rd >> 16;
    float s = 0.f;
    unsigned int j = 0;
    for (; j + 4 <= cnt; j += 4) {
        unsigned int i0 = __builtin_nontemporal_load(lst + j);
        unsigned int i1 = __builtin_nontemporal_load(lst + j + 1);
        unsigned int i2 = __builtin_nontemporal_load(lst + j + 2);
        unsigned int i3 = __builtin_nontemporal_load(lst + j + 3);
        s += (__half2float(zs[i0]) + __half2float(zs[i1]))
           + (__half2float(zs[i2]) + __half2float(zs[i3]));
    }
    for (; j < cnt; j++) s += __half2float(zs[lst[j]]);
    out[n] += s * u0[n].w;
}

extern "C" void kernel_launch(void* const* d_in, const int* in_sizes, int n_in,
                              void* d_out, int out_size, void* d_ws, size_t ws_size,
                              hipStream_t stream) {
    const float* x  = (const float*)d_in[0];
    const float* y1 = (const float*)d_in[1];
    const int*   ei = (const int*)d_in[2];
    const float* W1 = (const float*)d_in[3];
    const float* b1 = (const float*)d_in[4];
    const float* W2 = (const float*)d_in[5];
    const float* b2 = (const float*)d_in[6];
    const float* W3 = (const float*)d_in[7];
    const float* b3 = (const float*)d_in[8];
    float* out = (float*)d_out;

    int N = in_sizes[1];
    int E = in_sizes[2] / 2;
    const int* src = ei;
    const int* dst = ei + E;

    size_t Ns = (size_t)N;
    int nb = (N + BN2 - 1) >> BSH2;               // 245 coarse buckets (<=256)
    size_t segtot = (size_t)256 * CAPB;           // ~10.5M entries

    float* ws = (float*)d_ws;
    float4*       u0     = (float4*)ws;                              // 4N floats
    __half*       zs     = (__half*)(ws + 4 * Ns);                   // N halves (N floats rsvd)
    unsigned int* rowdeg = (unsigned int*)(ws + 5 * Ns);             // N
    uint2*        u0h    = (uint2*)(ws + 6 * Ns);                    // 2N floats
    unsigned int* gcur   = (unsigned int*)(ws + 8 * Ns);             // 256
    unsigned int* ebuf   = gcur + 256;                               // segtot
    unsigned int* ebuf2  = ebuf + segtot;                            // segtot
    uint4*        h1s    = (uint4*)(ebuf2 + segtot);                 // 16N floats (fp16 rows)

    hipMemsetAsync(gcur, 0, 256 * sizeof(unsigned int), stream);

    const int gS = (E + SPLIT_CH - 1) / SPLIT_CH;
    const int gN = (N + 255) / 256;
    const int g4 = (4 * N + 255) / 256;
    split_kernel <<<gS, 256, 0, stream>>>(src, dst, gcur, ebuf, E);
    build_kernel <<<nb, 1024, 0, stream>>>(gcur, ebuf, x, y1, ebuf2, rowdeg, u0, u0h, N);
    layer1_kernel<<<gN, 256, 0, stream>>>(u0, u0h, rowdeg, ebuf2, W1, b1, h1s, N);
    pull2_kernel <<<g4, 256, 0, stream>>>((const float4*)h1s, rowdeg, ebuf2, u0,
                                          x, y1, W2, b2, W3, b3, zs, out, N);
    pull3_kernel <<<gN, 256, 0, stream>>>(zs, u0, rowdeg, ebuf2, out, N);
}